// Round 20
// baseline (244.185 us; speedup 1.0000x reference)
//
#include <hip/hip_runtime.h>
#include <hip/hip_bf16.h>

typedef __attribute__((ext_vector_type(8))) short short8x;   // 8 x bf16 (4 VGPR) MFMA A/B frag
typedef __attribute__((ext_vector_type(4))) float f32x4;     // MFMA C/D frag

__device__ __forceinline__ ushort f2bf(float f){
  union { __hip_bfloat16 b; ushort u; } cvt;
  cvt.b = __float2bfloat16(f);                // RNE
  return cvt.u;
}

// ---------------- merged fp32 -> bf16 convert: all 6 inputs in ONE launch -------------------
// dst regions are laid out contiguously in ws in input order, so dst index == flat i.
// x[8388608] | Wq[4194304]*qscl | Wd[1048576] | Wo[4194304] | Wuk[1048576] | Wuv[1048576]
__global__ __launch_bounds__(256)
void cvt_all(const float* __restrict__ x, const float* __restrict__ Wq, const float* __restrict__ Wd,
             const float* __restrict__ Wo, const float* __restrict__ Wuk, const float* __restrict__ Wuv,
             ushort* __restrict__ out, float qscl){
  const long i = ((long)blockIdx.x * 256 + threadIdx.x) * 4;
  const float* src; long off; float scale = 1.0f;
  if      (i < 8388608L)  { src = x;   off = 0L; }
  else if (i < 12582912L) { src = Wq;  off = 8388608L;  scale = qscl; }
  else if (i < 13631488L) { src = Wd;  off = 12582912L; }
  else if (i < 17825792L) { src = Wo;  off = 13631488L; }
  else if (i < 18874368L) { src = Wuk; off = 17825792L; }
  else                    { src = Wuv; off = 18874368L; }
  const float4 v = *(const float4*)(src + (i - off));
  ushort4 o;
  o.x = f2bf(v.x * scale); o.y = f2bf(v.y * scale); o.z = f2bf(v.z * scale); o.w = f2bf(v.w * scale);
  *(ushort4*)(out + i) = o;
}

// ---------------- generic bf16 GEMM: C = A[M,K] * B  with B given as BT[N,K] ----------------
// 128x128 tile, BK=32, 4 waves (2x2), double-buffered LDS staged via global_load_lds(16B).
// XCD-aware block swizzle (T1). Counted-vmcnt depth-2 pipeline (round-17 verified).
template<int OUTBF>
__global__ __launch_bounds__(256, 4)
void gemm_bt(const ushort* __restrict__ A, const ushort* __restrict__ BT, void* __restrict__ Cv,
             int M, int N, int K, int lda, int ldb, int ldc,
             long aZ, long bZ, long cZ, float scale)
{
  __shared__ __align__(16) ushort As[2][128 * 32];
  __shared__ __align__(16) ushort Bs[2][128 * 32];
  const int z = blockIdx.z;
  const ushort* Ab = A + (long)z * aZ;
  const ushort* Bb = BT + (long)z * bZ;
  const int tid = threadIdx.x, lane = tid & 63, w = tid >> 6;
  const int wm = w >> 1, wn = w & 1;
  const int lq = lane & 15, q4 = lane >> 4;

  int lin = blockIdx.x + gridDim.x * blockIdx.y;
  const int cpx = (gridDim.x * gridDim.y) >> 3;
  lin = (lin & 7) * cpx + (lin >> 3);
  const int bx = lin % gridDim.x, by = lin / gridDim.x;

  const long arow = (long)by * 128, brow = (long)bx * 128;
  const int lr = lane >> 2, lc = (lane & 3) * 8;

  const f32x4 z4 = {0.f, 0.f, 0.f, 0.f};
  f32x4 acc[4][4];
#pragma unroll
  for (int i = 0; i < 4; i++)
#pragma unroll
    for (int j = 0; j < 4; j++) acc[i][j] = z4;

  auto stage = [&](int buf, int kt){                 // 4 global_load_lds per call
    const int k0 = kt * 32;
#pragma unroll
    for (int is = 0; is < 2; ++is){
      const int rb = is * 64 + w * 16;
      const ushort* ga = Ab + (arow + rb + lr) * (long)lda + k0 + lc;
      const ushort* gb = Bb + (brow + rb + lr) * (long)ldb + k0 + lc;
      __builtin_amdgcn_global_load_lds((const __attribute__((address_space(1))) void*)ga,
                                       (__attribute__((address_space(3))) void*)&As[buf][rb * 32], 16, 0, 0);
      __builtin_amdgcn_global_load_lds((const __attribute__((address_space(1))) void*)gb,
                                       (__attribute__((address_space(3))) void*)&Bs[buf][rb * 32], 16, 0, 0);
    }
  };

  const int nk = K >> 5;                              // nk >= 16 for all launches here
  stage(0, 0);
  stage(1, 1);
#pragma unroll 1
  for (int kt = 0; kt < nk; ++kt){
    if (kt == nk - 1) asm volatile("s_waitcnt vmcnt(0)" ::: "memory");
    else              asm volatile("s_waitcnt vmcnt(4)" ::: "memory");
    __syncthreads();
    const int buf = kt & 1;
    short8x a[4], b[4];
#pragma unroll
    for (int i = 0; i < 4; i++){
      a[i] = *(const short8x*)&As[buf][(wm * 64 + i * 16 + lq) * 32 + q4 * 8];
      b[i] = *(const short8x*)&Bs[buf][(wn * 64 + i * 16 + lq) * 32 + q4 * 8];
    }
#pragma unroll
    for (int i = 0; i < 4; i++)
#pragma unroll
      for (int j = 0; j < 4; j++)
        acc[i][j] = __builtin_amdgcn_mfma_f32_16x16x32_bf16(a[i], b[j], acc[i][j], 0, 0, 0);
    __syncthreads();                                  // all reads of buf done
    if (kt + 2 < nk) stage(buf, kt + 2);              // overwrite buf with tile kt+2
  }

  const long crowb = arow + wm * 64;
  const long ccolb = brow + wn * 64;
#pragma unroll
  for (int i = 0; i < 4; i++)
#pragma unroll
    for (int j = 0; j < 4; j++)
#pragma unroll
      for (int r = 0; r < 4; r++){
        const long row = crowb + i * 16 + q4 * 4 + r;
        const long col = ccolb + j * 16 + lq;
        const float v = acc[i][j][r] * scale;
        if (OUTBF) ((ushort*)Cv)[(long)z * cZ + row * ldc + col] = f2bf(v);
        else       ((float*)Cv)[(long)z * cZ + row * ldc + col] = v;
      }
}

// ---------------- flash attention v17: depth-3 K/V rotation, SINGLE barrier per step --------
// flash14 (session-best 76.4us) with the bottom barrier removed: 3 LDS buffers rotate so the
// stage issued at step tt targets buf((tt+2)%3) — the buffer whose reads all waves completed
// at step tt-1, which the TOP barrier of step tt already guarantees (a wave cannot arrive at
// the barrier before its PV MFMAs issued, which requires its ds_reads complete). Per step:
// vmcnt(4) -> barrier -> stage(tt+2) -> QK/exp2/pack -> lgkm -> PV. Barriers halve (2 -> 1).
// LDS 54272B -> 3 blocks/CU (12 waves, (256,3), VGPR ~56 << 170 cap).
// All other pieces verbatim from flash14: 1024 blocks, 4 waves x 16 q-rows, KVBLK=32, zigzag
// LPT, XCD-local bh, K granule^(row&7) swizzle, V granule^((row>>1)&3) swizzle, Pl pad 40.
__global__ __launch_bounds__(256, 3)
void flash17_kernel(const ushort* __restrict__ q, const ushort* __restrict__ k,
                    const ushort* __restrict__ vT, ushort* __restrict__ attnO)
{
  __shared__ __align__(16) ushort Kb[3][32 * 128];   // [t][d] swizzled granules, 8KB each
  __shared__ __align__(16) ushort Vb[3][128 * 32];   // [d][t] granule-XOR swizzled, 8KB each
  __shared__ __align__(16) ushort Pl[4][16][40];     // [w][s][t+pad], 5KB

  const int tid = threadIdx.x, lane = tid & 63, w = tid >> 6;   // w = 0..3
  const int lq = lane & 15, q4 = lane >> 4;

  const int blk = blockIdx.x;
  const int bh = (blk & 7) * 4 + ((blk >> 3) & 3);
  const int g = blk >> 5;                    // 0..31
  const int u = (g & 7) * 4 + (g >> 3);      // slot id; {g,g+8,g+16,g+24} -> consecutive u
  const int strip = (u & 1) ? (u >> 1) : (31 - (u >> 1));   // zigzag: balanced per-CU sums
  const int b = bh & 1, h = bh >> 1;

  const int nt = 2 * strip + 2;              // 32-wide t-tiles staged by this block
  const int wdiag = strip * 2 + (w >> 1);    // wave's diagonal tile
  const int moff = (w & 1) * 16;             // wave's row offset within diag tile

  const ushort* kb_ = k + (long)b * 2048 * 2048 + h * 128;        // row t stride 2048
  const ushort* vb_ = vT + (long)h * 128 * 4096 + (long)b * 2048; // row d stride 4096

  // hoisted staging addresses (is-offsets compile-time; both swizzles is/w-invariant)
  const int krow0 = w * 4 + (lane >> 4);                          // is adds 16
  const int kg = (lane & 15) ^ (krow0 & 7);
  const ushort* kbase = kb_ + (long)krow0 * 2048 + kg * 8;

  const int drow0 = w * 16 + (lane >> 2);                         // is adds 64
  const int vg = (lane & 3) ^ ((lane >> 3) & 3);                  // = (lane&3) ^ ((drow0>>1)&3)
  const ushort* vbase = vb_ + (long)drow0 * 4096 + vg * 8;

  auto stage = [&](int buf, int tt){
    const ushort* kp = kbase + (long)tt * 32 * 2048;
    const ushort* vp = vbase + (long)tt * 32;
#pragma unroll
    for (int is = 0; is < 2; ++is){
      __builtin_amdgcn_global_load_lds((const __attribute__((address_space(1))) void*)(kp + (long)is * 16 * 2048),
          (__attribute__((address_space(3))) void*)&Kb[buf][w * 512 + is * 2048], 16, 0, 0);
      __builtin_amdgcn_global_load_lds((const __attribute__((address_space(1))) void*)(vp + (long)is * 64 * 4096),
          (__attribute__((address_space(3))) void*)&Vb[buf][w * 512 + is * 2048], 16, 0, 0);
    }
  };

  const f32x4 z4 = {0.f, 0.f, 0.f, 0.f};

  const int qrow0 = strip * 64 + w * 16;
  const long qgbase = (long)b * 2048 + qrow0;

  // Q B-frags (16 rows): s = qrow0+lq, d = ks*32+q4*8+j ; fused q|lat buffer stride 2560
  short8x qf[4];
  {
    const ushort* qp = q + (qgbase + lq) * 2560 + h * 128 + q4 * 8;
#pragma unroll
    for (int ks = 0; ks < 4; ks++) qf[ks] = *(const short8x*)(qp + ks * 32);
  }

  f32x4 oacc[8];                             // O^T[d = dt*16 + q4*4 + r][s = lq]
#pragma unroll
  for (int dt = 0; dt < 8; dt++) oacc[dt] = z4;
  float dsum = 0.f;

  const int rxv = (lq >> 1) & 3;             // V read-side swizzle key ((r>>1)&3, dt-invariant)

  stage(0, 0);
  stage(1, 1);          // nt >= 2 always

  int cur = 0;          // tt % 3
#pragma unroll 1
  for (int tt = 0; tt < nt; ++tt){
    if (tt == nt - 1) asm volatile("s_waitcnt vmcnt(0)" ::: "memory");
    else              asm volatile("s_waitcnt vmcnt(4)" ::: "memory");
    __syncthreads();                         // buf(cur) ready; all reads of buf((tt+2)%3) done
    const int sb = (cur == 0) ? 2 : (cur - 1);   // (tt+2) % 3
    if (tt + 2 < nt) stage(sb, tt + 2);          // safe: last read at step tt-1, before barrier

    if (tt <= wdiag){
      const bool diag = (tt == wdiag);
      // QK + exp2 + pack, per ti (t-subtile of 16)
#pragma unroll
      for (int ti = 0; ti < 2; ++ti){
        const int r = ti * 16 + lq;
        const int rb = r * 128;
        const int rx = lq & 7;
        const short8x a0 = *(const short8x*)&Kb[cur][rb + (((q4) ^ rx) * 8)];
        const short8x a1 = *(const short8x*)&Kb[cur][rb + (((4 + q4) ^ rx) * 8)];
        const short8x a2 = *(const short8x*)&Kb[cur][rb + (((8 + q4) ^ rx) * 8)];
        const short8x a3 = *(const short8x*)&Kb[cur][rb + (((12 + q4) ^ rx) * 8)];
        f32x4 st = __builtin_amdgcn_mfma_f32_16x16x32_bf16(a0, qf[0], z4, 0, 0, 0);
        st = __builtin_amdgcn_mfma_f32_16x16x32_bf16(a1, qf[1], st, 0, 0, 0);
        st = __builtin_amdgcn_mfma_f32_16x16x32_bf16(a2, qf[2], st, 0, 0, 0);
        st = __builtin_amdgcn_mfma_f32_16x16x32_bf16(a3, qf[3], st, 0, 0, 0);
        ushort4 pb;
#pragma unroll
        for (int r4 = 0; r4 < 4; ++r4){
          const int tl = ti * 16 + q4 * 4 + r4;
          float p = exp2f(st[r4]);
          if (diag && tl > moff + lq) p = 0.f;
          dsum += p;
          ((ushort*)&pb)[r4] = f2bf(p);
        }
        *(ushort4*)&Pl[w][lq][ti * 16 + q4 * 4] = pb;
      }
      asm volatile("s_waitcnt lgkmcnt(0)" ::: "memory");
      __builtin_amdgcn_sched_barrier(0);
      const short8x pf = *(const short8x*)&Pl[w][lq][q4 * 8];   // P^T[t=q4*8+j][s=lq]
      __builtin_amdgcn_sched_barrier(0);
      // PV: O^T[d][s] += V^T[d][t] * P^T[t][s], k=32; V at swizzled granule q4^rxv
#pragma unroll
      for (int dt = 0; dt < 8; ++dt){
        const short8x av = *(const short8x*)&Vb[cur][(dt * 16 + lq) * 32 + ((q4 ^ rxv) * 8)];
        oacc[dt] = __builtin_amdgcn_mfma_f32_16x16x32_bf16(av, pf, oacc[dt], 0, 0, 0);
      }
    }
    cur = (cur == 2) ? 0 : (cur + 1);
  }

  dsum += __shfl_xor(dsum, 16);
  dsum += __shfl_xor(dsum, 32);
  const float inv = 1.f / dsum;

#pragma unroll
  for (int dt = 0; dt < 8; dt++){
    ushort4 o;
    o.x = f2bf(oacc[dt][0] * inv);
    o.y = f2bf(oacc[dt][1] * inv);
    o.z = f2bf(oacc[dt][2] * inv);
    o.w = f2bf(oacc[dt][3] * inv);
    *(ushort4*)(attnO + (qgbase + lq) * 2048 + h * 128 + dt * 16 + q4 * 4) = o;
  }
}

// ---------------- host launcher ----------------
extern "C" void kernel_launch(void* const* d_in, const int* in_sizes, int n_in,
                              void* d_out, int out_size, void* d_ws, size_t ws_size,
                              hipStream_t stream)
{
  const float* x   = (const float*)d_in[0];
  const float* Wd  = (const float*)d_in[1];
  const float* Wuk = (const float*)d_in[2];
  const float* Wuv = (const float*)d_in[3];
  const float* Wq  = (const float*)d_in[4];
  const float* Wo  = (const float*)d_in[5];
  float* out = (float*)d_out;
  ushort* ws = (ushort*)d_ws;

  ushort* xb    = ws + 0L;          // [4096][2048]
  ushort* wqdb  = ws + 8388608L;    // [2560][2048]: rows 0..2047 = Wq*(log2e/sqrt(128)), 2048..2559 = Wd
  ushort* wob   = ws + 13631488L;   // [2048(m)][2048(h,d)]
  ushort* wukb  = ws + 17825792L;   // [2048(h,d)][512(c)]
  ushort* wuvb  = ws + 18874368L;   // [2048(h,d)][512(c)]
  ushort* qlat  = ws + 19922944L;   // [4096][2560]: cols 0..2047 = q (pre-scaled), 2048..2559 = lat
  ushort* kb    = ws + 30408704L;   // [4096(b,t)][2048(h,d)]
  ushort* vTb   = ws + 38797312L;   // [2048(h,d)][4096(b,t)]
  ushort* attnO = ws + 47185920L;   // [4096(b,s)][2048(h,d)]

  // log2(e)/sqrt(128): folded into Wq so flash uses exp2 (identical softmax)
  const float QSCL = 0.12751744800f;

  // all six fp32->bf16 converts in one launch (dst regions contiguous in ws)
  cvt_all<<<19456, 256, 0, stream>>>(x, Wq, Wd, Wo, Wuk, Wuv, ws, QSCL);

  // fused q|lat = x @ [Wq' | Wd]^T : [4096, 2560]
  gemm_bt<1><<<dim3(20, 32, 1), 256, 0, stream>>>(xb, wqdb, qlat, 4096, 2560, 2048,
      2048, 2048, 2560, 0L, 0L, 0L, 1.0f);
  // k = lat @ Wuk^T : [4096, 2048]   (lat = qlat cols 2048.., lda 2560)
  gemm_bt<1><<<dim3(16, 32, 1), 256, 0, stream>>>(qlat + 2048, wukb, kb, 4096, 2048, 512,
      2560, 512, 2048, 0L, 0L, 0L, 1.0f);
  // vT = Wuv @ lat^T : [2048(h,d)][4096(b,t)]
  gemm_bt<1><<<dim3(32, 16, 1), 256, 0, stream>>>(wuvb, qlat + 2048, vTb, 2048, 4096, 512,
      512, 2560, 4096, 0L, 0L, 0L, 1.0f);
  // flash attention (causal, d=128): attnO [4096][2048]
  flash17_kernel<<<1024, 256, 0, stream>>>(qlat, kb, vTb, attnO);
  // out = attnO @ Wo^T : fp32 [4096, 2048]
  gemm_bt<0><<<dim3(16, 32, 1), 256, 0, stream>>>(attnO, wob, out, 4096, 2048, 2048,
      2048, 2048, 2048, 0L, 0L, 0L, 1.0f);
}

// Round 21
// 224.931 us; speedup vs baseline: 1.0856x; 1.0856x over previous
//
#include <hip/hip_runtime.h>
#include <hip/hip_bf16.h>

typedef __attribute__((ext_vector_type(8))) short short8x;   // 8 x bf16 (4 VGPR) MFMA A/B frag
typedef __attribute__((ext_vector_type(4))) float f32x4;     // MFMA C/D frag

__device__ __forceinline__ ushort f2bf(float f){
  union { __hip_bfloat16 b; ushort u; } cvt;
  cvt.b = __float2bfloat16(f);                // RNE
  return cvt.u;
}

// ---------------- merged fp32 -> bf16 convert: all 6 inputs in ONE launch -------------------
// dst regions are laid out contiguously in ws in input order, so dst index == flat i.
// x[8388608] | Wq[4194304]*qscl | Wd[1048576] | Wo[4194304] | Wuk[1048576] | Wuv[1048576]
__global__ __launch_bounds__(256)
void cvt_all(const float* __restrict__ x, const float* __restrict__ Wq, const float* __restrict__ Wd,
             const float* __restrict__ Wo, const float* __restrict__ Wuk, const float* __restrict__ Wuv,
             ushort* __restrict__ out, float qscl){
  const long i = ((long)blockIdx.x * 256 + threadIdx.x) * 4;
  const float* src; long off; float scale = 1.0f;
  if      (i < 8388608L)  { src = x;   off = 0L; }
  else if (i < 12582912L) { src = Wq;  off = 8388608L;  scale = qscl; }
  else if (i < 13631488L) { src = Wd;  off = 12582912L; }
  else if (i < 17825792L) { src = Wo;  off = 13631488L; }
  else if (i < 18874368L) { src = Wuk; off = 17825792L; }
  else                    { src = Wuv; off = 18874368L; }
  const float4 v = *(const float4*)(src + (i - off));
  ushort4 o;
  o.x = f2bf(v.x * scale); o.y = f2bf(v.y * scale); o.z = f2bf(v.z * scale); o.w = f2bf(v.w * scale);
  *(ushort4*)(out + i) = o;
}

// ---------------- generic bf16 GEMM: C = A[M,K] * B  with B given as BT[N,K] ----------------
// 128x128 tile, BK=32, 4 waves (2x2), double-buffered LDS staged via global_load_lds(16B).
// XCD-aware block swizzle (T1). Counted-vmcnt depth-2 pipeline (round-17 verified).
template<int OUTBF>
__global__ __launch_bounds__(256, 4)
void gemm_bt(const ushort* __restrict__ A, const ushort* __restrict__ BT, void* __restrict__ Cv,
             int M, int N, int K, int lda, int ldb, int ldc,
             long aZ, long bZ, long cZ, float scale)
{
  __shared__ __align__(16) ushort As[2][128 * 32];
  __shared__ __align__(16) ushort Bs[2][128 * 32];
  const int z = blockIdx.z;
  const ushort* Ab = A + (long)z * aZ;
  const ushort* Bb = BT + (long)z * bZ;
  const int tid = threadIdx.x, lane = tid & 63, w = tid >> 6;
  const int wm = w >> 1, wn = w & 1;
  const int lq = lane & 15, q4 = lane >> 4;

  int lin = blockIdx.x + gridDim.x * blockIdx.y;
  const int cpx = (gridDim.x * gridDim.y) >> 3;
  lin = (lin & 7) * cpx + (lin >> 3);
  const int bx = lin % gridDim.x, by = lin / gridDim.x;

  const long arow = (long)by * 128, brow = (long)bx * 128;
  const int lr = lane >> 2, lc = (lane & 3) * 8;

  const f32x4 z4 = {0.f, 0.f, 0.f, 0.f};
  f32x4 acc[4][4];
#pragma unroll
  for (int i = 0; i < 4; i++)
#pragma unroll
    for (int j = 0; j < 4; j++) acc[i][j] = z4;

  auto stage = [&](int buf, int kt){                 // 4 global_load_lds per call
    const int k0 = kt * 32;
#pragma unroll
    for (int is = 0; is < 2; ++is){
      const int rb = is * 64 + w * 16;
      const ushort* ga = Ab + (arow + rb + lr) * (long)lda + k0 + lc;
      const ushort* gb = Bb + (brow + rb + lr) * (long)ldb + k0 + lc;
      __builtin_amdgcn_global_load_lds((const __attribute__((address_space(1))) void*)ga,
                                       (__attribute__((address_space(3))) void*)&As[buf][rb * 32], 16, 0, 0);
      __builtin_amdgcn_global_load_lds((const __attribute__((address_space(1))) void*)gb,
                                       (__attribute__((address_space(3))) void*)&Bs[buf][rb * 32], 16, 0, 0);
    }
  };

  const int nk = K >> 5;                              // nk >= 16 for all launches here
  stage(0, 0);
  stage(1, 1);
#pragma unroll 1
  for (int kt = 0; kt < nk; ++kt){
    if (kt == nk - 1) asm volatile("s_waitcnt vmcnt(0)" ::: "memory");
    else              asm volatile("s_waitcnt vmcnt(4)" ::: "memory");
    __syncthreads();
    const int buf = kt & 1;
    short8x a[4], b[4];
#pragma unroll
    for (int i = 0; i < 4; i++){
      a[i] = *(const short8x*)&As[buf][(wm * 64 + i * 16 + lq) * 32 + q4 * 8];
      b[i] = *(const short8x*)&Bs[buf][(wn * 64 + i * 16 + lq) * 32 + q4 * 8];
    }
#pragma unroll
    for (int i = 0; i < 4; i++)
#pragma unroll
      for (int j = 0; j < 4; j++)
        acc[i][j] = __builtin_amdgcn_mfma_f32_16x16x32_bf16(a[i], b[j], acc[i][j], 0, 0, 0);
    __syncthreads();                                  // all reads of buf done
    if (kt + 2 < nk) stage(buf, kt + 2);              // overwrite buf with tile kt+2
  }

  const long crowb = arow + wm * 64;
  const long ccolb = brow + wn * 64;
#pragma unroll
  for (int i = 0; i < 4; i++)
#pragma unroll
    for (int j = 0; j < 4; j++)
#pragma unroll
      for (int r = 0; r < 4; r++){
        const long row = crowb + i * 16 + q4 * 4 + r;
        const long col = ccolb + j * 16 + lq;
        const float v = acc[i][j][r] * scale;
        if (OUTBF) ((ushort*)Cv)[(long)z * cZ + row * ldc + col] = f2bf(v);
        else       ((float*)Cv)[(long)z * cZ + row * ldc + col] = v;
      }
}

// ---------------- flash attention v14 (session-best 76.4 us, round-19 verified) -------------
// Final flash configuration after bracketing the design space on every axis:
// rows/wave {16,32,64}, blocks/CU {1,2,3,4}, barriers/step {1,2}, P-path {LDS,register},
// KVBLK {32,64} — this corner (16 rows, 4 blocks/CU, 2 barriers, LDS-P, KVBLK=32) beats all
// neighbors. 1024 blocks, 4 waves x 16 q-rows, zigzag LPT, XCD-local bh; K granule^(row&7)
// swizzle; V granule^((row>>1)&3) swizzle (both sides); Pl padded 40; counted vmcnt(4).
__global__ __launch_bounds__(256, 4)
void flash14_kernel(const ushort* __restrict__ q, const ushort* __restrict__ k,
                    const ushort* __restrict__ vT, ushort* __restrict__ attnO)
{
  __shared__ __align__(16) ushort Kb[2][32 * 128];   // [t][d] swizzled granules, 8KB each
  __shared__ __align__(16) ushort Vb[2][128 * 32];   // [d][t] granule-XOR swizzled, 8KB each
  __shared__ __align__(16) ushort Pl[4][16][40];     // [w][s][t+pad], 5KB

  const int tid = threadIdx.x, lane = tid & 63, w = tid >> 6;   // w = 0..3
  const int lq = lane & 15, q4 = lane >> 4;

  const int blk = blockIdx.x;
  const int bh = (blk & 7) * 4 + ((blk >> 3) & 3);
  const int g = blk >> 5;                    // 0..31
  const int u = (g & 7) * 4 + (g >> 3);      // slot id; {g,g+8,g+16,g+24} -> consecutive u
  const int strip = (u & 1) ? (u >> 1) : (31 - (u >> 1));   // zigzag: balanced per-CU sums
  const int b = bh & 1, h = bh >> 1;

  const int nt = 2 * strip + 2;              // 32-wide t-tiles staged by this block
  const int wdiag = strip * 2 + (w >> 1);    // wave's diagonal tile
  const int moff = (w & 1) * 16;             // wave's row offset within diag tile

  const ushort* kb_ = k + (long)b * 2048 * 2048 + h * 128;        // row t stride 2048
  const ushort* vb_ = vT + (long)h * 128 * 4096 + (long)b * 2048; // row d stride 4096

  // hoisted staging addresses (is-offsets compile-time; both swizzles is/w-invariant)
  const int krow0 = w * 4 + (lane >> 4);                          // is adds 16
  const int kg = (lane & 15) ^ (krow0 & 7);
  const ushort* kbase = kb_ + (long)krow0 * 2048 + kg * 8;

  const int drow0 = w * 16 + (lane >> 2);                         // is adds 64
  const int vg = (lane & 3) ^ ((lane >> 3) & 3);                  // = (lane&3) ^ ((drow0>>1)&3)
  const ushort* vbase = vb_ + (long)drow0 * 4096 + vg * 8;

  auto stage = [&](int buf, int tt){
    const ushort* kp = kbase + (long)tt * 32 * 2048;
    const ushort* vp = vbase + (long)tt * 32;
#pragma unroll
    for (int is = 0; is < 2; ++is){
      __builtin_amdgcn_global_load_lds((const __attribute__((address_space(1))) void*)(kp + (long)is * 16 * 2048),
          (__attribute__((address_space(3))) void*)&Kb[buf][w * 512 + is * 2048], 16, 0, 0);
      __builtin_amdgcn_global_load_lds((const __attribute__((address_space(1))) void*)(vp + (long)is * 64 * 4096),
          (__attribute__((address_space(3))) void*)&Vb[buf][w * 512 + is * 2048], 16, 0, 0);
    }
  };

  const f32x4 z4 = {0.f, 0.f, 0.f, 0.f};

  const int qrow0 = strip * 64 + w * 16;
  const long qgbase = (long)b * 2048 + qrow0;

  // Q B-frags (16 rows): s = qrow0+lq, d = ks*32+q4*8+j ; fused q|lat buffer stride 2560
  short8x qf[4];
  {
    const ushort* qp = q + (qgbase + lq) * 2560 + h * 128 + q4 * 8;
#pragma unroll
    for (int ks = 0; ks < 4; ks++) qf[ks] = *(const short8x*)(qp + ks * 32);
  }

  f32x4 oacc[8];                             // O^T[d = dt*16 + q4*4 + r][s = lq]
#pragma unroll
  for (int dt = 0; dt < 8; dt++) oacc[dt] = z4;
  float dsum = 0.f;

  const int rxv = (lq >> 1) & 3;             // V read-side swizzle key ((r>>1)&3, dt-invariant)

  stage(0, 0);
  stage(1, 1);          // nt >= 2 always

#pragma unroll 1
  for (int tt = 0; tt < nt; ++tt){
    if (tt == nt - 1) asm volatile("s_waitcnt vmcnt(0)" ::: "memory");
    else              asm volatile("s_waitcnt vmcnt(4)" ::: "memory");
    __syncthreads();
    const int cur = tt & 1;

    if (tt <= wdiag){
      const bool diag = (tt == wdiag);
      // QK + exp2 + pack, per ti (t-subtile of 16)
#pragma unroll
      for (int ti = 0; ti < 2; ++ti){
        const int r = ti * 16 + lq;
        const int rb = r * 128;
        const int rx = lq & 7;
        const short8x a0 = *(const short8x*)&Kb[cur][rb + (((q4) ^ rx) * 8)];
        const short8x a1 = *(const short8x*)&Kb[cur][rb + (((4 + q4) ^ rx) * 8)];
        const short8x a2 = *(const short8x*)&Kb[cur][rb + (((8 + q4) ^ rx) * 8)];
        const short8x a3 = *(const short8x*)&Kb[cur][rb + (((12 + q4) ^ rx) * 8)];
        f32x4 st = __builtin_amdgcn_mfma_f32_16x16x32_bf16(a0, qf[0], z4, 0, 0, 0);
        st = __builtin_amdgcn_mfma_f32_16x16x32_bf16(a1, qf[1], st, 0, 0, 0);
        st = __builtin_amdgcn_mfma_f32_16x16x32_bf16(a2, qf[2], st, 0, 0, 0);
        st = __builtin_amdgcn_mfma_f32_16x16x32_bf16(a3, qf[3], st, 0, 0, 0);
        ushort4 pb;
#pragma unroll
        for (int r4 = 0; r4 < 4; ++r4){
          const int tl = ti * 16 + q4 * 4 + r4;
          float p = exp2f(st[r4]);
          if (diag && tl > moff + lq) p = 0.f;
          dsum += p;
          ((ushort*)&pb)[r4] = f2bf(p);
        }
        *(ushort4*)&Pl[w][lq][ti * 16 + q4 * 4] = pb;
      }
      asm volatile("s_waitcnt lgkmcnt(0)" ::: "memory");
      __builtin_amdgcn_sched_barrier(0);
      const short8x pf = *(const short8x*)&Pl[w][lq][q4 * 8];   // P^T[t=q4*8+j][s=lq]
      __builtin_amdgcn_sched_barrier(0);
      // PV: O^T[d][s] += V^T[d][t] * P^T[t][s], k=32; V at swizzled granule q4^rxv
#pragma unroll
      for (int dt = 0; dt < 8; ++dt){
        const short8x av = *(const short8x*)&Vb[cur][(dt * 16 + lq) * 32 + ((q4 ^ rxv) * 8)];
        oacc[dt] = __builtin_amdgcn_mfma_f32_16x16x32_bf16(av, pf, oacc[dt], 0, 0, 0);
      }
    }
    __syncthreads();                        // all reads of buf[cur] complete
    if (tt + 2 < nt) stage(cur, tt + 2);    // overwrite buf[cur] = buf[(tt+2)&1]
  }

  dsum += __shfl_xor(dsum, 16);
  dsum += __shfl_xor(dsum, 32);
  const float inv = 1.f / dsum;

#pragma unroll
  for (int dt = 0; dt < 8; dt++){
    ushort4 o;
    o.x = f2bf(oacc[dt][0] * inv);
    o.y = f2bf(oacc[dt][1] * inv);
    o.z = f2bf(oacc[dt][2] * inv);
    o.w = f2bf(oacc[dt][3] * inv);
    *(ushort4*)(attnO + (qgbase + lq) * 2048 + h * 128 + dt * 16 + q4 * 4) = o;
  }
}

// ---------------- host launcher ----------------
extern "C" void kernel_launch(void* const* d_in, const int* in_sizes, int n_in,
                              void* d_out, int out_size, void* d_ws, size_t ws_size,
                              hipStream_t stream)
{
  const float* x   = (const float*)d_in[0];
  const float* Wd  = (const float*)d_in[1];
  const float* Wuk = (const float*)d_in[2];
  const float* Wuv = (const float*)d_in[3];
  const float* Wq  = (const float*)d_in[4];
  const float* Wo  = (const float*)d_in[5];
  float* out = (float*)d_out;
  ushort* ws = (ushort*)d_ws;

  ushort* xb    = ws + 0L;          // [4096][2048]
  ushort* wqdb  = ws + 8388608L;    // [2560][2048]: rows 0..2047 = Wq*(log2e/sqrt(128)), 2048..2559 = Wd
  ushort* wob   = ws + 13631488L;   // [2048(m)][2048(h,d)]
  ushort* wukb  = ws + 17825792L;   // [2048(h,d)][512(c)]
  ushort* wuvb  = ws + 18874368L;   // [2048(h,d)][512(c)]
  ushort* qlat  = ws + 19922944L;   // [4096][2560]: cols 0..2047 = q (pre-scaled), 2048..2559 = lat
  ushort* kb    = ws + 30408704L;   // [4096(b,t)][2048(h,d)]
  ushort* vTb   = ws + 38797312L;   // [2048(h,d)][4096(b,t)]
  ushort* attnO = ws + 47185920L;   // [4096(b,s)][2048(h,d)]

  // log2(e)/sqrt(128): folded into Wq so flash uses exp2 (identical softmax)
  const float QSCL = 0.12751744800f;

  // all six fp32->bf16 converts in one launch (dst regions contiguous in ws)
  cvt_all<<<19456, 256, 0, stream>>>(x, Wq, Wd, Wo, Wuk, Wuv, ws, QSCL);

  // fused q|lat = x @ [Wq' | Wd]^T : [4096, 2560]
  gemm_bt<1><<<dim3(20, 32, 1), 256, 0, stream>>>(xb, wqdb, qlat, 4096, 2560, 2048,
      2048, 2048, 2560, 0L, 0L, 0L, 1.0f);
  // k = lat @ Wuk^T : [4096, 2048]   (lat = qlat cols 2048.., lda 2560)
  gemm_bt<1><<<dim3(16, 32, 1), 256, 0, stream>>>(qlat + 2048, wukb, kb, 4096, 2048, 512,
      2560, 512, 2048, 0L, 0L, 0L, 1.0f);
  // vT = Wuv @ lat^T : [2048(h,d)][4096(b,t)]
  gemm_bt<1><<<dim3(32, 16, 1), 256, 0, stream>>>(wuvb, qlat + 2048, vTb, 2048, 4096, 512,
      512, 2560, 4096, 0L, 0L, 0L, 1.0f);
  // flash attention (causal, d=128): attnO [4096][2048]
  flash14_kernel<<<1024, 256, 0, stream>>>(qlat, kb, vTb, attnO);
  // out = attnO @ Wo^T : fp32 [4096, 2048]
  gemm_bt<0><<<dim3(16, 32, 1), 256, 0, stream>>>(attnO, wob, out, 4096, 2048, 2048,
      2048, 2048, 2048, 0L, 0L, 0L, 1.0f);
}